// Round 6
// baseline (1057.527 us; speedup 1.0000x reference)
//
#include <hip/hip_runtime.h>

// ---------------------------------------------------------------------------
// EPSparseMoeBlock: B=2, L=2048, D=2048, E=8, K=2, I=768, IS=4096, T=4096
// bf16 MFMA GEMMs (fp32 accum), fp32 router, sparse top-2 dispatch.
// R1: global_load_lds width=16 staging in both GEMMs.
// R2/R3: fused casts, router+h-cast, direct-to-out epilogues.
// R4: BK=64 dual-slab K-loop + merged down launch -> FAILED (store/atomic
//     race within one launch; merge removed the stream-order guarantee).
// R5: keep BK=64 dual-slab; revert to TWO down launches (shared store first,
//     then expert atomicAdd — ordering restored).
// ---------------------------------------------------------------------------

#define T_TOK 4096
#define DIM   2048
#define NEXP  8
#define IEXP  768
#define ISHR  4096

typedef __attribute__((ext_vector_type(8))) short bf16x8_t;  // 8 bf16 (4 VGPR)
typedef __attribute__((ext_vector_type(4))) float f32x4_t;   // MFMA acc

__device__ __forceinline__ unsigned short f2bf(float f) {
    unsigned int u = __float_as_uint(f);
    u += 0x7fffu + ((u >> 16) & 1u);   // round-to-nearest-even
    return (unsigned short)(u >> 16);
}

// async global->LDS, 16 B per lane; lds dest must be wave-uniform base,
// HW scatters lane i at base + i*16 (m97/m104 semantics).
__device__ __forceinline__ void gl2lds16(const unsigned short* g, unsigned short* l) {
    __builtin_amdgcn_global_load_lds(
        (const __attribute__((address_space(1))) unsigned int*)g,
        (__attribute__((address_space(3))) unsigned int*)l, 16, 0, 0);
}

// --- fused weight casts fp32 -> bf16 (5 tensors) + cnt zeroing -------------
#define C0 6291456   // gup   (8*1536*2048)/4
#define C1 9437184   // + dnp (8*2048*768)/4
#define C2 11534336  // + sgw (4096*2048)/4
#define C3 13631488  // + suw
#define C4 15728640  // + sdw
__global__ __launch_bounds__(256) void fused_cast_kernel(
    const float* __restrict__ s0, const float* __restrict__ s1,
    const float* __restrict__ s2, const float* __restrict__ s3,
    const float* __restrict__ s4,
    unsigned short* __restrict__ d0, unsigned short* __restrict__ d1,
    unsigned short* __restrict__ d2, unsigned short* __restrict__ d3,
    unsigned short* __restrict__ d4, int* __restrict__ cnt) {
    if (blockIdx.x == 0 && threadIdx.x < NEXP) cnt[threadIdx.x] = 0;
    int i = blockIdx.x * 256 + threadIdx.x;
    const float* src; unsigned short* dst; int base;
    if      (i < C0) { src = s0; dst = d0; base = 0;  }
    else if (i < C1) { src = s1; dst = d1; base = C0; }
    else if (i < C2) { src = s2; dst = d2; base = C1; }
    else if (i < C3) { src = s3; dst = d3; base = C2; }
    else             { src = s4; dst = d4; base = C3; }
    int j = i - base;
    float4 v = ((const float4*)src)[j];
    short4 r;
    r.x = (short)f2bf(v.x); r.y = (short)f2bf(v.y);
    r.z = (short)f2bf(v.z); r.w = (short)f2bf(v.w);
    ((short4*)dst)[j] = r;
}

// --- router: fp32 logits, top-2, renorm, scatter lists; also emits h_bf ----
__global__ __launch_bounds__(256) void router_kernel(
    const float* __restrict__ h, const float* __restrict__ gw,
    const float* __restrict__ segw,
    unsigned short* __restrict__ h_bf,
    float* __restrict__ sig, int* __restrict__ cnt,
    int* __restrict__ enc, float* __restrict__ wl) {
    int w = threadIdx.x >> 6, l = threadIdx.x & 63;
    int t = blockIdx.x * 4 + w;
    float p[9];
#pragma unroll
    for (int e = 0; e < 9; ++e) p[e] = 0.f;
    const float* hr = h + (size_t)t * DIM;
    unsigned short* hb = h_bf + (size_t)t * DIM;
    for (int i = 0; i < DIM; i += 64) {
        float x = hr[i + l];
        hb[i + l] = f2bf(x);          // fused h cast
#pragma unroll
        for (int e = 0; e < NEXP; ++e) p[e] += x * gw[e * DIM + i + l];
        p[8] += x * segw[i + l];
    }
#pragma unroll
    for (int off = 32; off > 0; off >>= 1) {
#pragma unroll
        for (int e = 0; e < 9; ++e) p[e] += __shfl_xor(p[e], off, 64);
    }
    if (l == 0) {
        int b1 = 0; float v1 = p[0];
        for (int e = 1; e < NEXP; ++e) if (p[e] > v1) { v1 = p[e]; b1 = e; }
        int b2 = -1; float v2 = -1e30f;
        for (int e = 0; e < NEXP; ++e)
            if (e != b1 && p[e] > v2) { v2 = p[e]; b2 = e; }
        float w1 = 1.f / (1.f + __expf(v2 - v1));
        int pos = atomicAdd(&cnt[b1], 1);
        enc[b1 * T_TOK + pos] = 2 * t;     wl[b1 * T_TOK + pos] = w1;
        pos = atomicAdd(&cnt[b2], 1);
        enc[b2 * T_TOK + pos] = 2 * t + 1; wl[b2 * T_TOK + pos] = 1.f - w1;
        sig[t] = 1.f / (1.f + __expf(-p[8]));
    }
}

// --- fused gate+up GEMM: out[p, n] = silu(h.Wg[n]) * h.Wu[n]  (bf16 out) ---
// BM=128 (gathered tokens), 64 gate rows + paired 64 up rows, BK=64 (2 slabs)
__global__ __launch_bounds__(256) void gemm_gateup(
    const unsigned short* __restrict__ hA,        // [T, D] bf16
    const unsigned short* __restrict__ gate_base,
    const unsigned short* __restrict__ up_base,
    size_t w_estride,
    const int* __restrict__ enc_list,             // null => identity gather
    const int* __restrict__ cnt_arr,              // null => full 4096
    unsigned short* __restrict__ out_base,
    size_t out_estride, int ldo) {
    const int Kdim = DIM;
    int e = blockIdx.z;
    int cnt = cnt_arr ? cnt_arr[e] : T_TOK;
    int m0 = blockIdx.x * 128;
    if (m0 >= cnt) return;
    int n0 = blockIdx.y * 64;
    const unsigned short* Wg = gate_base + (size_t)e * w_estride;
    const unsigned short* Wu = up_base + (size_t)e * w_estride;
    const int* lst = enc_list ? (enc_list + e * T_TOK) : nullptr;

    // two 32-col slabs, each with the proven 64B-row layout
    __shared__ __align__(16) unsigned short As[2][128 * 32];
    __shared__ __align__(16) unsigned short Bs[2][128 * 32];

    int tid = threadIdx.x;
    int w = tid >> 6, l = tid & 63;
    int lrow = l >> 2, lcol = (l & 3) << 3;

    const unsigned short* aptr[2];
    const unsigned short* bptr[2];
    int loff[2];
#pragma unroll
    for (int s = 0; s < 2; ++s) {
        int r = ((w + 4 * s) << 4) + lrow;        // tile row 0..127
        int pp = m0 + r; if (pp >= cnt) pp = cnt - 1;
        int tk = lst ? (lst[pp] >> 1) : pp;
        aptr[s] = hA + (size_t)tk * Kdim + lcol;
        bptr[s] = (r < 64) ? (Wg + (size_t)(n0 + r) * Kdim + lcol)
                           : (Wu + (size_t)(n0 + r - 64) * Kdim + lcol);
        loff[s] = ((w + 4 * s) << 4) * 32;        // wave-uniform chunk base
    }

    f32x4_t zero4 = {0.f, 0.f, 0.f, 0.f};
    f32x4_t acc[2][8];
#pragma unroll
    for (int i = 0; i < 2; ++i)
#pragma unroll
        for (int j = 0; j < 8; ++j) acc[i][j] = zero4;

    int lane15 = l & 15, q = l >> 4;

    for (int k0 = 0; k0 < Kdim; k0 += 64) {
        __syncthreads();
#pragma unroll
        for (int kk = 0; kk < 2; ++kk) {
            gl2lds16(aptr[0] + k0 + kk * 32, &As[kk][loff[0]]);
            gl2lds16(aptr[1] + k0 + kk * 32, &As[kk][loff[1]]);
            gl2lds16(bptr[0] + k0 + kk * 32, &Bs[kk][loff[0]]);
            gl2lds16(bptr[1] + k0 + kk * 32, &Bs[kk][loff[1]]);
        }
        __syncthreads();
#pragma unroll
        for (int kk = 0; kk < 2; ++kk) {
            bf16x8_t a[2], b[8];
#pragma unroll
            for (int i = 0; i < 2; ++i)
                a[i] = *(const bf16x8_t*)&As[kk][(32 * w + 16 * i + lane15) * 32 + q * 8];
#pragma unroll
            for (int j = 0; j < 8; ++j)
                b[j] = *(const bf16x8_t*)&Bs[kk][(16 * j + lane15) * 32 + q * 8];
#pragma unroll
            for (int i = 0; i < 2; ++i)
#pragma unroll
                for (int j = 0; j < 8; ++j)
                    acc[i][j] = __builtin_amdgcn_mfma_f32_16x16x32_bf16(
                        a[i], b[j], acc[i][j], 0, 0, 0);
        }
    }

#pragma unroll
    for (int i = 0; i < 2; ++i) {
#pragma unroll
        for (int r = 0; r < 4; ++r) {
            int p = m0 + 32 * w + 16 * i + q * 4 + r;   // list position, <4096
            unsigned short* orow = out_base + (size_t)e * out_estride
                                 + (size_t)p * ldo + n0 + lane15;
#pragma unroll
            for (int j = 0; j < 4; ++j) {
                float g = acc[i][j][r];
                float u = acc[i][j + 4][r];
                float sv = (g / (1.f + __expf(-g))) * u;
                orow[16 * j] = f2bf(sv);
            }
        }
    }
}

// --- down GEMM: scale(p) * act[p,:] . W[n,:] -> out (store or atomicAdd) ---
// BK=64 dual-slab K-loop. MUST be launched separately for shared (store)
// then experts (atomicAdd): stream order is the only write-order guarantee.
__global__ __launch_bounds__(256) void gemm_down(
    const unsigned short* __restrict__ Abase, size_t a_estride,
    const unsigned short* __restrict__ Wbase, size_t w_estride,
    const int* __restrict__ enc_list, const int* __restrict__ cnt_arr,
    const float* __restrict__ wlist,              // per-p scale (sig or wl)
    float* __restrict__ Obase, int Kdim, int use_atomic) {
    int e = blockIdx.z;
    int cnt = cnt_arr ? cnt_arr[e] : T_TOK;
    int m0 = blockIdx.x * 128;
    if (m0 >= cnt) return;
    int n0 = blockIdx.y * 128;
    const unsigned short* A = Abase + (size_t)e * a_estride;
    const unsigned short* W = Wbase + (size_t)e * w_estride;

    __shared__ __align__(16) unsigned short As[2][128 * 32];
    __shared__ __align__(16) unsigned short Bs[2][128 * 32];

    int tid = threadIdx.x;
    int w = tid >> 6, l = tid & 63;
    int lrow = l >> 2, lcol = (l & 3) << 3;

    const unsigned short* aptr[2];
    const unsigned short* bptr[2];
    int loff[2];
#pragma unroll
    for (int s = 0; s < 2; ++s) {
        int r = ((w + 4 * s) << 4) + lrow;
        aptr[s] = A + (size_t)(m0 + r) * Kdim + lcol;
        bptr[s] = W + (size_t)(n0 + r) * Kdim + lcol;
        loff[s] = ((w + 4 * s) << 4) * 32;
    }

    f32x4_t zero4 = {0.f, 0.f, 0.f, 0.f};
    f32x4_t acc[2][8];
#pragma unroll
    for (int i = 0; i < 2; ++i)
#pragma unroll
        for (int j = 0; j < 8; ++j) acc[i][j] = zero4;

    int lane15 = l & 15, q = l >> 4;

    for (int k0 = 0; k0 < Kdim; k0 += 64) {
        __syncthreads();
#pragma unroll
        for (int kk = 0; kk < 2; ++kk) {
            gl2lds16(aptr[0] + k0 + kk * 32, &As[kk][loff[0]]);
            gl2lds16(aptr[1] + k0 + kk * 32, &As[kk][loff[1]]);
            gl2lds16(bptr[0] + k0 + kk * 32, &Bs[kk][loff[0]]);
            gl2lds16(bptr[1] + k0 + kk * 32, &Bs[kk][loff[1]]);
        }
        __syncthreads();
#pragma unroll
        for (int kk = 0; kk < 2; ++kk) {
            bf16x8_t a[2], b[8];
#pragma unroll
            for (int i = 0; i < 2; ++i)
                a[i] = *(const bf16x8_t*)&As[kk][(32 * w + 16 * i + lane15) * 32 + q * 8];
#pragma unroll
            for (int j = 0; j < 8; ++j)
                b[j] = *(const bf16x8_t*)&Bs[kk][(16 * j + lane15) * 32 + q * 8];
#pragma unroll
            for (int i = 0; i < 2; ++i)
#pragma unroll
                for (int j = 0; j < 8; ++j)
                    acc[i][j] = __builtin_amdgcn_mfma_f32_16x16x32_bf16(
                        a[i], b[j], acc[i][j], 0, 0, 0);
        }
    }

#pragma unroll
    for (int i = 0; i < 2; ++i) {
#pragma unroll
        for (int r = 0; r < 4; ++r) {
            int p = m0 + 32 * w + 16 * i + q * 4 + r;
            if (p < cnt) {
                int dest = enc_list ? (enc_list[e * T_TOK + p] >> 1) : p;
                float sc = wlist[e * T_TOK + p];
                float* orow = Obase + (size_t)dest * DIM + n0 + lane15;
                if (use_atomic) {
#pragma unroll
                    for (int j = 0; j < 8; ++j)
                        atomicAdd(&orow[16 * j], sc * acc[i][j][r]);
                } else {
#pragma unroll
                    for (int j = 0; j < 8; ++j)
                        orow[16 * j] = sc * acc[i][j][r];
                }
            }
        }
    }
}

extern "C" void kernel_launch(void* const* d_in, const int* in_sizes, int n_in,
                              void* d_out, int out_size, void* d_ws, size_t ws_size,
                              hipStream_t stream) {
    (void)in_sizes; (void)n_in; (void)out_size; (void)ws_size;
    const float* h    = (const float*)d_in[0];  // [2,2048,2048]
    const float* gw   = (const float*)d_in[1];  // [8,2048]
    const float* gup  = (const float*)d_in[2];  // [8,1536,2048]
    const float* dnp  = (const float*)d_in[3];  // [8,2048,768]
    const float* sgw  = (const float*)d_in[4];  // [4096,2048]
    const float* suw  = (const float*)d_in[5];  // [4096,2048]
    const float* sdw  = (const float*)d_in[6];  // [2048,4096]
    const float* segw = (const float*)d_in[7];  // [1,2048]
    float* out = (float*)d_out;

    char* ws = (char*)d_ws;
    size_t off = 0;
    auto alloc = [&](size_t bytes) {
        void* p = ws + off;
        off += (bytes + 255) & ~(size_t)255;
        return p;
    };
    unsigned short* h_bf   = (unsigned short*)alloc((size_t)T_TOK * DIM * 2);
    unsigned short* wgu_bf = (unsigned short*)alloc((size_t)NEXP * 2 * IEXP * DIM * 2);
    unsigned short* wdn_bf = (unsigned short*)alloc((size_t)NEXP * DIM * IEXP * 2);
    unsigned short* wsg_bf = (unsigned short*)alloc((size_t)ISHR * DIM * 2);
    unsigned short* wsu_bf = (unsigned short*)alloc((size_t)ISHR * DIM * 2);
    unsigned short* wsd_bf = (unsigned short*)alloc((size_t)DIM * ISHR * 2);
    unsigned short* act_s  = (unsigned short*)alloc((size_t)T_TOK * ISHR * 2);
    unsigned short* act_e  = (unsigned short*)alloc((size_t)NEXP * T_TOK * IEXP * 2);
    float* sig     = (float*)alloc((size_t)T_TOK * 4);
    int*   cnt     = (int*)alloc(NEXP * 4);
    int*   enc     = (int*)alloc((size_t)NEXP * T_TOK * 4);
    float* wl      = (float*)alloc((size_t)NEXP * T_TOK * 4);

    // 1. fused weight casts (also zeroes cnt)
    fused_cast_kernel<<<C4 / 256, 256, 0, stream>>>(
        gup, dnp, sgw, suw, sdw,
        wgu_bf, wdn_bf, wsg_bf, wsu_bf, wsd_bf, cnt);

    // 2. router (fp32 logits; also emits h_bf)
    router_kernel<<<T_TOK / 4, 256, 0, stream>>>(
        h, gw, segw, h_bf, sig, cnt, enc, wl);

    // 3. shared gate+up -> act_s bf16
    gemm_gateup<<<dim3(T_TOK / 128, ISHR / 64, 1), 256, 0, stream>>>(
        h_bf, wsg_bf, wsu_bf, 0, nullptr, nullptr, act_s, 0, ISHR);

    // 4. expert gate+up (gathered) -> act_e bf16
    gemm_gateup<<<dim3(T_TOK / 128, IEXP / 64, NEXP), 256, 0, stream>>>(
        h_bf, wgu_bf, wgu_bf + (size_t)IEXP * DIM, (size_t)2 * IEXP * DIM,
        enc, cnt, act_e, (size_t)T_TOK * IEXP, IEXP);

    // 5. shared down: out[t,:] = sig[t] * (act_s . Wd^T)  (plain store)
    gemm_down<<<dim3(T_TOK / 128, DIM / 128, 1), 256, 0, stream>>>(
        act_s, 0, wsd_bf, 0, nullptr, nullptr, sig, out, ISHR, 0);

    // 6. expert down: out[t,:] += wl * (act_e . Wd^T)  (atomicAdd, after 5)
    gemm_down<<<dim3(T_TOK / 128, DIM / 128, NEXP), 256, 0, stream>>>(
        act_e, (size_t)T_TOK * IEXP, wdn_bf, (size_t)DIM * IEXP,
        enc, cnt, wl, out, IEXP, 1);
}

// Round 7
// 1014.794 us; speedup vs baseline: 1.0421x; 1.0421x over previous
//
#include <hip/hip_runtime.h>

// ---------------------------------------------------------------------------
// EPSparseMoeBlock: B=2, L=2048, D=2048, E=8, K=2, I=768, IS=4096, T=4096
// bf16 MFMA GEMMs (fp32 accum), fp32 router, sparse top-2 dispatch.
// R1: global_load_lds width=16 staging (BK=32, 16KB LDS — proven).
// R4/R5 post-mortem: BK=64 regressed (occupancy loss > barrier gain); merged
//   store+atomic down raced. R6: revert BK=32; make down ALL-atomic onto a
//   pre-zeroed out (zeroing fused into cast launch, stream-ordered), so the
//   down merge is correct; also merge both gateup GEMMs into one launch.
// 4 launches: cast(+zero out,cnt) -> router(+h cast) -> gateup_all -> down_all
// ---------------------------------------------------------------------------

#define T_TOK 4096
#define DIM   2048
#define NEXP  8
#define IEXP  768
#define ISHR  4096

typedef __attribute__((ext_vector_type(8))) short bf16x8_t;  // 8 bf16 (4 VGPR)
typedef __attribute__((ext_vector_type(4))) float f32x4_t;   // MFMA acc

__device__ __forceinline__ unsigned short f2bf(float f) {
    unsigned int u = __float_as_uint(f);
    u += 0x7fffu + ((u >> 16) & 1u);   // round-to-nearest-even
    return (unsigned short)(u >> 16);
}

// async global->LDS, 16 B per lane; lds dest must be wave-uniform base,
// HW scatters lane i at base + i*16 (m97/m104 semantics).
__device__ __forceinline__ void gl2lds16(const unsigned short* g, unsigned short* l) {
    __builtin_amdgcn_global_load_lds(
        (const __attribute__((address_space(1))) unsigned int*)g,
        (__attribute__((address_space(3))) unsigned int*)l, 16, 0, 0);
}

// --- fused weight casts fp32 -> bf16 (5 tensors) + cnt zero + out zero -----
#define C0 6291456   // gup   (8*1536*2048)/4
#define C1 9437184   // + dnp (8*2048*768)/4
#define C2 11534336  // + sgw (4096*2048)/4
#define C3 13631488  // + suw
#define C4 15728640  // + sdw
#define NOUT4 2097152 // (4096*2048)/4 out floats4 to zero
__global__ __launch_bounds__(256) void fused_cast_kernel(
    const float* __restrict__ s0, const float* __restrict__ s1,
    const float* __restrict__ s2, const float* __restrict__ s3,
    const float* __restrict__ s4,
    unsigned short* __restrict__ d0, unsigned short* __restrict__ d1,
    unsigned short* __restrict__ d2, unsigned short* __restrict__ d3,
    unsigned short* __restrict__ d4, int* __restrict__ cnt,
    float* __restrict__ out_zero) {
    if (blockIdx.x == 0 && threadIdx.x < NEXP) cnt[threadIdx.x] = 0;
    int i = blockIdx.x * 256 + threadIdx.x;
    if (i < NOUT4) {
        float4 z = {0.f, 0.f, 0.f, 0.f};
        ((float4*)out_zero)[i] = z;
    }
    const float* src; unsigned short* dst; int base;
    if      (i < C0) { src = s0; dst = d0; base = 0;  }
    else if (i < C1) { src = s1; dst = d1; base = C0; }
    else if (i < C2) { src = s2; dst = d2; base = C1; }
    else if (i < C3) { src = s3; dst = d3; base = C2; }
    else             { src = s4; dst = d4; base = C3; }
    int j = i - base;
    float4 v = ((const float4*)src)[j];
    short4 r;
    r.x = (short)f2bf(v.x); r.y = (short)f2bf(v.y);
    r.z = (short)f2bf(v.z); r.w = (short)f2bf(v.w);
    ((short4*)dst)[j] = r;
}

// --- router: fp32 logits, top-2, renorm, scatter lists; also emits h_bf ----
__global__ __launch_bounds__(256) void router_kernel(
    const float* __restrict__ h, const float* __restrict__ gw,
    const float* __restrict__ segw,
    unsigned short* __restrict__ h_bf,
    float* __restrict__ sig, int* __restrict__ cnt,
    int* __restrict__ enc, float* __restrict__ wl) {
    int w = threadIdx.x >> 6, l = threadIdx.x & 63;
    int t = blockIdx.x * 4 + w;
    float p[9];
#pragma unroll
    for (int e = 0; e < 9; ++e) p[e] = 0.f;
    const float* hr = h + (size_t)t * DIM;
    unsigned short* hb = h_bf + (size_t)t * DIM;
    for (int i = 0; i < DIM; i += 64) {
        float x = hr[i + l];
        hb[i + l] = f2bf(x);          // fused h cast
#pragma unroll
        for (int e = 0; e < NEXP; ++e) p[e] += x * gw[e * DIM + i + l];
        p[8] += x * segw[i + l];
    }
#pragma unroll
    for (int off = 32; off > 0; off >>= 1) {
#pragma unroll
        for (int e = 0; e < 9; ++e) p[e] += __shfl_xor(p[e], off, 64);
    }
    if (l == 0) {
        int b1 = 0; float v1 = p[0];
        for (int e = 1; e < NEXP; ++e) if (p[e] > v1) { v1 = p[e]; b1 = e; }
        int b2 = -1; float v2 = -1e30f;
        for (int e = 0; e < NEXP; ++e)
            if (e != b1 && p[e] > v2) { v2 = p[e]; b2 = e; }
        float w1 = 1.f / (1.f + __expf(v2 - v1));
        int pos = atomicAdd(&cnt[b1], 1);
        enc[b1 * T_TOK + pos] = 2 * t;     wl[b1 * T_TOK + pos] = w1;
        pos = atomicAdd(&cnt[b2], 1);
        enc[b2 * T_TOK + pos] = 2 * t + 1; wl[b2 * T_TOK + pos] = 1.f - w1;
        sig[t] = 1.f / (1.f + __expf(-p[8]));
    }
}

// --- merged gate+up GEMM (shared + all experts in one launch) --------------
// z<64: shared expert, n0=z*64. z>=64: expert e=(z-64)/12, n0=((z-64)%12)*64.
// Per block: BM=128 tokens, 64 gate rows + paired 64 up rows, BK=32 (proven).
__global__ __launch_bounds__(256) void gemm_gateup_all(
    const unsigned short* __restrict__ hA,
    const unsigned short* __restrict__ wsg, const unsigned short* __restrict__ wsu,
    const unsigned short* __restrict__ wgu,
    const int* __restrict__ enc, const int* __restrict__ cnt_arr,
    unsigned short* __restrict__ act_s, unsigned short* __restrict__ act_e) {
    const int Kdim = DIM;
    int z = blockIdx.z;
    const unsigned short *Wg, *Wu;
    const int* lst; int cnt, n0, ldo;
    unsigned short* outp;
    if (z < 64) {
        n0 = z * 64; Wg = wsg; Wu = wsu;
        lst = nullptr; cnt = T_TOK; outp = act_s; ldo = ISHR;
    } else {
        int zz = z - 64;
        int e = zz / 12, ny = zz % 12;
        n0 = ny * 64;
        Wg = wgu + (size_t)e * 2 * IEXP * DIM;
        Wu = Wg + (size_t)IEXP * DIM;
        lst = enc + e * T_TOK; cnt = cnt_arr[e];
        outp = act_e + (size_t)e * T_TOK * IEXP; ldo = IEXP;
    }
    int m0 = blockIdx.x * 128;
    if (m0 >= cnt) return;

    __shared__ __align__(16) unsigned short As[128 * 32];
    __shared__ __align__(16) unsigned short Bs[128 * 32];

    int tid = threadIdx.x;
    int w = tid >> 6, l = tid & 63;
    int lrow = l >> 2, lcol = (l & 3) << 3;

    const unsigned short* aptr[2];
    const unsigned short* bptr[2];
    unsigned short* alds[2];
    unsigned short* blds[2];
#pragma unroll
    for (int s = 0; s < 2; ++s) {
        int r = ((w + 4 * s) << 4) + lrow;        // tile row 0..127
        int pp = m0 + r; if (pp >= cnt) pp = cnt - 1;
        int tk = lst ? (lst[pp] >> 1) : pp;
        aptr[s] = hA + (size_t)tk * Kdim + lcol;
        bptr[s] = (r < 64) ? (Wg + (size_t)(n0 + r) * Kdim + lcol)
                           : (Wu + (size_t)(n0 + r - 64) * Kdim + lcol);
        alds[s] = &As[((w + 4 * s) << 4) * 32];   // wave-uniform base
        blds[s] = &Bs[((w + 4 * s) << 4) * 32];
    }

    f32x4_t zero4 = {0.f, 0.f, 0.f, 0.f};
    f32x4_t acc[2][8];
#pragma unroll
    for (int i = 0; i < 2; ++i)
#pragma unroll
        for (int j = 0; j < 8; ++j) acc[i][j] = zero4;

    int lane15 = l & 15, q = l >> 4;

    for (int k0 = 0; k0 < Kdim; k0 += 32) {
        __syncthreads();
        gl2lds16(aptr[0] + k0, alds[0]);
        gl2lds16(aptr[1] + k0, alds[1]);
        gl2lds16(bptr[0] + k0, blds[0]);
        gl2lds16(bptr[1] + k0, blds[1]);
        __syncthreads();
        bf16x8_t a[2], b[8];
#pragma unroll
        for (int i = 0; i < 2; ++i)
            a[i] = *(const bf16x8_t*)&As[(32 * w + 16 * i + lane15) * 32 + q * 8];
#pragma unroll
        for (int j = 0; j < 8; ++j)
            b[j] = *(const bf16x8_t*)&Bs[(16 * j + lane15) * 32 + q * 8];
#pragma unroll
        for (int i = 0; i < 2; ++i)
#pragma unroll
            for (int j = 0; j < 8; ++j)
                acc[i][j] = __builtin_amdgcn_mfma_f32_16x16x32_bf16(
                    a[i], b[j], acc[i][j], 0, 0, 0);
    }

#pragma unroll
    for (int i = 0; i < 2; ++i) {
#pragma unroll
        for (int r = 0; r < 4; ++r) {
            int p = m0 + 32 * w + 16 * i + q * 4 + r;   // list position, <4096
            unsigned short* orow = outp + (size_t)p * ldo + n0 + lane15;
#pragma unroll
            for (int j = 0; j < 4; ++j) {
                float g = acc[i][j][r];
                float u = acc[i][j + 4][r];
                float sv = (g / (1.f + __expf(-g))) * u;
                orow[16 * j] = f2bf(sv);
            }
        }
    }
}

// --- merged down GEMM, ALL-atomic onto pre-zeroed out ----------------------
// z=0: shared (A=act_s, K=ISHR, scale=sig[t]); z>=1: expert e=z-1
// (A=act_e gathered rows, K=IEXP, scale=wl, dest=enc>>1). out += sc*acc.
__global__ __launch_bounds__(256) void gemm_down_all(
    const unsigned short* __restrict__ act_s,
    const unsigned short* __restrict__ wsd,
    const unsigned short* __restrict__ act_e,
    const unsigned short* __restrict__ wdn,
    const int* __restrict__ enc, const int* __restrict__ cnt_arr,
    const float* __restrict__ wlst, const float* __restrict__ sig,
    float* __restrict__ out) {
    int z = blockIdx.z;
    const unsigned short *A, *W;
    const int* lst; const float* scl;
    int Kdim, cnt;
    if (z == 0) {
        A = act_s; W = wsd; Kdim = ISHR; cnt = T_TOK;
        lst = nullptr; scl = sig;
    } else {
        int e = z - 1;
        A = act_e + (size_t)e * T_TOK * IEXP;
        W = wdn + (size_t)e * DIM * IEXP;
        Kdim = IEXP; cnt = cnt_arr[e];
        lst = enc + e * T_TOK; scl = wlst + (size_t)e * T_TOK;
    }
    int m0 = blockIdx.x * 128;
    if (m0 >= cnt) return;
    int n0 = blockIdx.y * 128;

    __shared__ __align__(16) unsigned short As[128 * 32];
    __shared__ __align__(16) unsigned short Bs[128 * 32];

    int tid = threadIdx.x;
    int w = tid >> 6, l = tid & 63;
    int lrow = l >> 2, lcol = (l & 3) << 3;

    const unsigned short* aptr[2];
    const unsigned short* bptr[2];
    unsigned short* alds[2];
    unsigned short* blds[2];
#pragma unroll
    for (int s = 0; s < 2; ++s) {
        int r = ((w + 4 * s) << 4) + lrow;
        int pp = m0 + r; if (pp >= cnt) pp = cnt - 1;
        aptr[s] = A + (size_t)pp * Kdim + lcol;
        bptr[s] = W + (size_t)(n0 + r) * Kdim + lcol;
        alds[s] = &As[((w + 4 * s) << 4) * 32];
        blds[s] = &Bs[((w + 4 * s) << 4) * 32];
    }

    f32x4_t zero4 = {0.f, 0.f, 0.f, 0.f};
    f32x4_t acc[2][8];
#pragma unroll
    for (int i = 0; i < 2; ++i)
#pragma unroll
        for (int j = 0; j < 8; ++j) acc[i][j] = zero4;

    int lane15 = l & 15, q = l >> 4;

    for (int k0 = 0; k0 < Kdim; k0 += 32) {
        __syncthreads();
        gl2lds16(aptr[0] + k0, alds[0]);
        gl2lds16(aptr[1] + k0, alds[1]);
        gl2lds16(bptr[0] + k0, blds[0]);
        gl2lds16(bptr[1] + k0, blds[1]);
        __syncthreads();
        bf16x8_t a[2], b[8];
#pragma unroll
        for (int i = 0; i < 2; ++i)
            a[i] = *(const bf16x8_t*)&As[(32 * w + 16 * i + lane15) * 32 + q * 8];
#pragma unroll
        for (int j = 0; j < 8; ++j)
            b[j] = *(const bf16x8_t*)&Bs[(16 * j + lane15) * 32 + q * 8];
#pragma unroll
        for (int i = 0; i < 2; ++i)
#pragma unroll
            for (int j = 0; j < 8; ++j)
                acc[i][j] = __builtin_amdgcn_mfma_f32_16x16x32_bf16(
                    a[i], b[j], acc[i][j], 0, 0, 0);
    }

#pragma unroll
    for (int i = 0; i < 2; ++i) {
#pragma unroll
        for (int r = 0; r < 4; ++r) {
            int p = m0 + 32 * w + 16 * i + q * 4 + r;
            if (p < cnt) {
                int dest = lst ? (lst[p] >> 1) : p;
                float sc = scl[p];
                float* orow = out + (size_t)dest * DIM + n0 + lane15;
#pragma unroll
                for (int j = 0; j < 8; ++j)
                    atomicAdd(&orow[16 * j], sc * acc[i][j][r]);
            }
        }
    }
}

extern "C" void kernel_launch(void* const* d_in, const int* in_sizes, int n_in,
                              void* d_out, int out_size, void* d_ws, size_t ws_size,
                              hipStream_t stream) {
    (void)in_sizes; (void)n_in; (void)out_size; (void)ws_size;
    const float* h    = (const float*)d_in[0];  // [2,2048,2048]
    const float* gw   = (const float*)d_in[1];  // [8,2048]
    const float* gup  = (const float*)d_in[2];  // [8,1536,2048]
    const float* dnp  = (const float*)d_in[3];  // [8,2048,768]
    const float* sgw  = (const float*)d_in[4];  // [4096,2048]
    const float* suw  = (const float*)d_in[5];  // [4096,2048]
    const float* sdw  = (const float*)d_in[6];  // [2048,4096]
    const float* segw = (const float*)d_in[7];  // [1,2048]
    float* out = (float*)d_out;

    char* ws = (char*)d_ws;
    size_t off = 0;
    auto alloc = [&](size_t bytes) {
        void* p = ws + off;
        off += (bytes + 255) & ~(size_t)255;
        return p;
    };
    unsigned short* h_bf   = (unsigned short*)alloc((size_t)T_TOK * DIM * 2);
    unsigned short* wgu_bf = (unsigned short*)alloc((size_t)NEXP * 2 * IEXP * DIM * 2);
    unsigned short* wdn_bf = (unsigned short*)alloc((size_t)NEXP * DIM * IEXP * 2);
    unsigned short* wsg_bf = (unsigned short*)alloc((size_t)ISHR * DIM * 2);
    unsigned short* wsu_bf = (unsigned short*)alloc((size_t)ISHR * DIM * 2);
    unsigned short* wsd_bf = (unsigned short*)alloc((size_t)DIM * ISHR * 2);
    unsigned short* act_s  = (unsigned short*)alloc((size_t)T_TOK * ISHR * 2);
    unsigned short* act_e  = (unsigned short*)alloc((size_t)NEXP * T_TOK * IEXP * 2);
    float* sig     = (float*)alloc((size_t)T_TOK * 4);
    int*   cnt     = (int*)alloc(NEXP * 4);
    int*   enc     = (int*)alloc((size_t)NEXP * T_TOK * 4);
    float* wl      = (float*)alloc((size_t)NEXP * T_TOK * 4);

    // 1. fused weight casts + zero cnt + zero out (stream-ordered before down)
    fused_cast_kernel<<<C4 / 256, 256, 0, stream>>>(
        gup, dnp, sgw, suw, sdw,
        wgu_bf, wdn_bf, wsg_bf, wsu_bf, wsd_bf, cnt, out);

    // 2. router (fp32 logits; also emits h_bf)
    router_kernel<<<T_TOK / 4, 256, 0, stream>>>(
        h, gw, segw, h_bf, sig, cnt, enc, wl);

    // 3. all gate+up GEMMs in one launch: z<64 shared, z>=64 experts
    gemm_gateup_all<<<dim3(T_TOK / 128, 1, 64 + 12 * NEXP), 256, 0, stream>>>(
        h_bf, wsg_bf, wsu_bf, wgu_bf, enc, cnt, act_s, act_e);

    // 4. all down GEMMs in one launch, all atomicAdd onto zeroed out
    gemm_down_all<<<dim3(T_TOK / 128, DIM / 128, 1 + NEXP), 256, 0, stream>>>(
        act_s, wsd_bf, act_e, wdn_bf, enc, cnt, wl, sig, out);
}